// Round 11
// baseline (1050.364 us; speedup 1.0000x reference)
//
#include <hip/hip_runtime.h>
#include <math.h>

#define BB   8
#define TT   12

typedef _Float16 f16;
typedef f16  f16x8 __attribute__((ext_vector_type(8)));
typedef float f32x4 __attribute__((ext_vector_type(4)));

// ws layout (byte offsets) — halo image is 66*68 = 4488 positions
#define OFF_WT3  0ull            // 8*6*3*64*104*2      = 1,916,928
#define OFF_WC   1916928ull      // 9*128*8*4           = 36,864    -> 1,953,792
#define OFF_XP   1953792ull      // 8*66*68*64*2        = 4,595,712 -> 6,549,504
#define OFF_HA   6549504ull      // 8*66*68*128*2       = 9,191,424 -> 15,740,928
#define OFF_HB   15740928ull     // 9,191,424           -> 24,932,352
#define OFF_C    24932352ull     // 8*64*64*128*4       = 16,777,216 -> 41,709,568
#define WS_END   41709568ull
#define ZERO_BYTES (WS_END - OFF_XP)   // xp + hA + hB + c = 39,755,776

#define A_BYTES  31680           // 396 pos * 40 f16 * 2B (6 rows x 66 cols)
#define BSL_BYTES 13312          // 64 co * 104 k * 2B  (one dy-slice)

__device__ inline void gload16(const void* g, void* l) {
    // LDS dest is the WAVE-UNIFORM base; HW adds lane*16.
    __builtin_amdgcn_global_load_lds((const __attribute__((address_space(1))) void*)g,
                                     (__attribute__((address_space(3))) void*)l, 16, 0, 0);
}

__device__ inline float sigm_fast(float x) {
    return 1.f / (1.f + __expf(-x));
}
__device__ inline float tanh_fast(float x) {
    float xx = fminf(fmaxf(x, -15.f), 15.f);
    float e = __expf(2.f * xx);
    return (e - 1.f) / (e + 1.f);
}

__global__ __launch_bounds__(256) void zero_kernel(float4* __restrict__ p, int n4) {
    int i = blockIdx.x * blockDim.x + threadIdx.x;
    int stride = gridDim.x * blockDim.x;
    for (; i < n4; i += stride) p[i] = make_float4(0.f, 0.f, 0.f, 0.f);
}

// w_lstm (512,192,3,3) fp32 -> wT3 f16 [nt(8)][chunk(6)][dy(3)][co_l(64)][k(104)]
// co' = hid*4+gate (co' = nt*64+co_l), k = dx*32 + ci_l (k>=96 zero pad)
__global__ __launch_bounds__(256) void wprep(const float* __restrict__ w, f16* __restrict__ wT3) {
    int t = blockIdx.x * 256 + threadIdx.x;
    if (t >= 8 * 6 * 3 * 64 * 104) return;
    int k    = t % 104;
    int r    = t / 104;
    int co_l = r & 63;
    int r2   = r >> 6;
    int dy    = r2 % 3;
    int chunk = (r2 / 3) % 6;
    int ntl   = r2 / 18;
    f16 val = (f16)0.f;
    if (k < 96) {
        int dx = k >> 5, ci_l = k & 31;
        int ci  = chunk * 32 + ci_l;          // concat(x:0..63, h:64..191) order
        int cop = ntl * 64 + co_l;
        int hid = cop >> 2, gate = cop & 3;
        val = (f16)w[((size_t)(gate * 128 + hid) * 192 + ci) * 9 + dy * 3 + dx];
    }
    wT3[t] = val;
}

// w_conv (5,128,3,3) -> wc f32 [tap(9)][ci(128)][8] (cls padded)
__global__ __launch_bounds__(256) void wcprep(const float* __restrict__ w, float* __restrict__ wc) {
    int t = blockIdx.x * 256 + threadIdx.x;
    if (t >= 9216) return;
    int cls = t & 7, ci = (t >> 3) & 127, tap = t >> 10;
    wc[t] = (cls < 5) ? w[(size_t)(cls * 128 + ci) * 9 + tap] : 0.f;
}

// x_t NCHW fp32 -> NHWC f16 with halo: xp[b][y+1][x+1][ci], dims [8][66][68][64]
__global__ __launch_bounds__(256) void xprep(const float* __restrict__ x, f16* __restrict__ xp, int t) {
    int pos = blockIdx.x * 256 + threadIdx.x;     // 32768
    int b = pos >> 12, rr = pos & 4095, y = rr >> 6, xx = rr & 63;
    const float* s = x + ((size_t)(b * TT + t) * 64) * 4096 + y * 64 + xx;
    f16* d = xp + (((size_t)b * 66 + y + 1) * 68 + xx + 1) * 64;
    #pragma unroll
    for (int c8 = 0; c8 < 8; ++c8) {
        f16x8 v;
        #pragma unroll
        for (int e = 0; e < 8; ++e) v[e] = (f16)s[(size_t)(c8 * 8 + e) * 4096];
        *(f16x8*)&d[c8 * 8] = v;
    }
}

__device__ inline float pickc(f32x4 v, int j) {
    return j == 0 ? v[0] : j == 1 ? v[1] : j == 2 ? v[2] : v[3];
}

// Fused gates-GEMM (implicit im2col, f16 MFMA) + LSTM pointwise epilogue.
// Block: 256 pos (4 rows) x 64 co'. 4 waves, each = 1 image row x 64 co'.
// B split by dy into 3 DMA-linear slices; 2 rotating slice buffers so the
// DMA for phase p+1 flies during phase p's compute -> no serial stage wait.
// LDS 58.3 KB -> 2 blocks/CU. bid = nt*128 + mt (XCD affinity on mt).
__global__ __launch_bounds__(256, 2) void gemm_step(
    const f16* __restrict__ xp, const f16* __restrict__ hin,
    const f16* __restrict__ wT3, const float* __restrict__ b_lstm,
    float* __restrict__ c_st, f16* __restrict__ hout)
{
    __shared__ __align__(16) char smem[A_BYTES + 2 * BSL_BYTES];   // 58,304 B
    f16* As = (f16*)smem;
    char* Bbuf0 = smem + A_BYTES;
    char* Bbuf1 = smem + A_BYTES + BSL_BYTES;

    const int tid  = threadIdx.x;
    const int lane = tid & 63;
    const int wid  = tid >> 6;                // 0..3 = image row within slab
    const int l15  = lane & 15, lg = lane >> 4;

    const int bid = blockIdx.x;
    const int nt  = bid >> 7;                 // 0..7
    const int mt  = bid & 127;                // 0..127
    const int b   = mt >> 4;
    const int yr  = (mt & 15) << 2;           // first image row of 4-row slab

    const int rowbase = (b * 66 + yr) * 68;   // halo-image position base
    const f16* wslice = wT3 + (size_t)nt * (6 * 3 * 64 * 104);

    f32x4 acc[4][4] = {};
    f16x8 areg[7];

    // ---- hoisted im2col addressing (chunk-invariant): 1584 items = 396 pc x 4 ci8
    int po[7], wo[7], c8o[7];
    bool av[7];
    #pragma unroll
    for (int i = 0; i < 7; ++i) {
        int idx = i * 256 + tid;
        av[i] = idx < 1584;
        int ci8 = idx & 3;
        int pc  = idx >> 2;                 // 0..395 = r*66+c
        int r   = (pc * 497) >> 15;         // /66 exact for pc<396
        int c   = pc - r * 66;
        po[i]  = rowbase + r * 68 + c;
        c8o[i] = ci8 * 8;
        wo[i]  = pc * 40 + ci8 * 8;
    }

    auto loadA = [&](int cc) {
        if (cc < 2) {
            const f16* src = xp + cc * 32;
            #pragma unroll
            for (int i = 0; i < 7; ++i)
                if (av[i]) areg[i] = *(const f16x8*)(src + ((size_t)po[i] << 6) + c8o[i]);
        } else {
            const f16* src = hin + (cc * 32 - 64);
            #pragma unroll
            for (int i = 0; i < 7; ++i)
                if (av[i]) areg[i] = *(const f16x8*)(src + ((size_t)po[i] << 7) + c8o[i]);
        }
    };
    auto writeA = [&]() {
        #pragma unroll
        for (int i = 0; i < 7; ++i)
            if (av[i]) *(f16x8*)&As[wo[i]] = areg[i];
    };
    // stage one dy-slice (phase index ph = cc*3+dy) into Bs
    auto stageB = [&](int ph, char* Bs) {
        const char* bsrc = (const char*)wslice + (size_t)ph * BSL_BYTES;
        for (int k = wid; k < 13; k += 4)           // 13*1024 = 13,312 B
            gload16(bsrc + k * 1024 + lane * 16, Bs + k * 1024);
    };
    auto compute_dy = [&](int dy, const char* Bs) {
        const f16* Bsf = (const f16*)Bs;
        #pragma unroll
        for (int dx = 0; dx < 3; ++dx) {
            f16x8 a[4];
            #pragma unroll
            for (int mf = 0; mf < 4; ++mf)
                a[mf] = *(const f16x8*)&As[((wid + dy) * 66 + mf * 16 + l15 + dx) * 40 + lg * 8];
            f16x8 bf[4];
            #pragma unroll
            for (int nf = 0; nf < 4; ++nf)
                bf[nf] = *(const f16x8*)&Bsf[(nf * 16 + l15) * 104 + dx * 32 + lg * 8];
            #pragma unroll
            for (int mf = 0; mf < 4; ++mf)
                #pragma unroll
                for (int nf = 0; nf < 4; ++nf)
                    acc[mf][nf] = __builtin_amdgcn_mfma_f32_16x16x32_f16(a[mf], bf[nf], acc[mf][nf], 0, 0, 0);
        }
    };

    // ---- prologue: A chunk 0 + B phase 0 ----
    loadA(0);
    stageB(0, Bbuf0);
    writeA();
    __syncthreads();                       // drains B phase-0 DMA + A writes

    char* bufs[2] = { Bbuf0, Bbuf1 };
    int p = 0;                             // current phase = cc*3+dy

    #pragma unroll 1
    for (int cc = 0; cc < 6; ++cc) {
        if (cc < 5) loadA(cc + 1);         // global->reg, lands across dy phases
        #pragma unroll 1
        for (int dy = 0; dy < 3; ++dy) {
            if (p < 17) stageB(p + 1, bufs[(p + 1) & 1]);   // DMA next slice
            compute_dy(dy, bufs[p & 1]);
            __syncthreads();               // phase end: next-slice DMA drained
            ++p;
        }
        if (cc < 5) {
            writeA();                      // As single buffer: all reads done
            __syncthreads();
        }
    }

    // ---- LSTM epilogue: 4-gate exchange via shfl_xor within 4-lane groups ----
    const int q = lane & 3;   // gate index of this lane's column (co' = hid*4+gate)
    #pragma unroll
    for (int mf = 0; mf < 4; ++mf) {
        #pragma unroll
        for (int nf = 0; nf < 4; ++nf) {
            int hid = nt * 16 + nf * 4 + (l15 >> 2);
            float bias = b_lstm[q * 128 + hid];
            f32x4 v = acc[mf][nf];
            v[0] += bias; v[1] += bias; v[2] += bias; v[3] += bias;
            float own = pickc(v, q);
            float r1 = __shfl_xor(pickc(v, q ^ 1), 1);
            float r2 = __shfl_xor(pickc(v, q ^ 2), 2);
            float r3 = __shfl_xor(pickc(v, q ^ 3), 3);
            float gi = q == 0 ? own : (q == 1 ? r1 : q == 2 ? r2 : r3);
            float gf = q == 1 ? own : (q == 0 ? r1 : q == 3 ? r2 : r3);
            float go = q == 2 ? own : (q == 3 ? r1 : q == 0 ? r2 : r3);
            float gg = q == 3 ? own : (q == 2 ? r1 : q == 1 ? r2 : r3);
            float i_ = sigm_fast(gi);
            float f_ = sigm_fast(gf);
            float o_ = sigm_fast(go);
            float g_ = tanh_fast(gg);
            int px = mf * 16 + lg * 4 + q;         // C row = lg*4 + reg(q)
            int py = yr + wid;
            size_t ic = (((size_t)b * 64 + py) * 64 + px) * 128 + hid;
            float cv = f_ * c_st[ic] + i_ * g_;
            c_st[ic] = cv;
            float hv = o_ * tanh_fast(cv);
            hout[(((size_t)b * 66 + py + 1) * 68 + (px + 1)) * 128 + hid] = (f16)hv;
        }
    }
}

// Final 3x3 conv (128 -> 5) over NHWC f16 h + channelwise log_softmax (NCHW out)
__global__ __launch_bounds__(256) void final_conv(
    const f16* __restrict__ h, const float* __restrict__ wc,
    const float* __restrict__ b_conv, float* __restrict__ out)
{
    __shared__ float swc[9216];
    for (int i = threadIdx.x; i < 9216; i += 256) swc[i] = wc[i];
    __syncthreads();
    int pos = blockIdx.x * 256 + threadIdx.x;
    int b = pos >> 12, rr = pos & 4095, y = rr >> 6, xx = rr & 63;
    float acc[5];
    #pragma unroll
    for (int cls = 0; cls < 5; ++cls) acc[cls] = b_conv[cls];
    #pragma unroll 1
    for (int tap = 0; tap < 9; ++tap) {
        int dy = tap / 3, dx = tap - dy * 3;
        const f16* hp = h + (((size_t)b * 66 + y + dy) * 68 + xx + dx) * 128;
        #pragma unroll
        for (int c16 = 0; c16 < 16; ++c16) {
            f16x8 v = *(const f16x8*)&hp[c16 * 8];
            #pragma unroll
            for (int e = 0; e < 8; ++e) {
                float hv = (float)v[e];
                const float* wp = &swc[(size_t)(tap * 128 + c16 * 8 + e) * 8];
                acc[0] = fmaf(hv, wp[0], acc[0]);
                acc[1] = fmaf(hv, wp[1], acc[1]);
                acc[2] = fmaf(hv, wp[2], acc[2]);
                acc[3] = fmaf(hv, wp[3], acc[3]);
                acc[4] = fmaf(hv, wp[4], acc[4]);
            }
        }
    }
    float m = acc[0];
    #pragma unroll
    for (int cls = 1; cls < 5; ++cls) m = fmaxf(m, acc[cls]);
    float s = 0.f;
    #pragma unroll
    for (int cls = 0; cls < 5; ++cls) s += __expf(acc[cls] - m);
    float lse = logf(s) + m;
    #pragma unroll
    for (int cls = 0; cls < 5; ++cls)
        out[((size_t)(b * 5 + cls) << 12) + (y << 6) + xx] = acc[cls] - lse;
}

extern "C" void kernel_launch(void* const* d_in, const int* in_sizes, int n_in,
                              void* d_out, int out_size, void* d_ws, size_t ws_size,
                              hipStream_t stream) {
    const float* x      = (const float*)d_in[0];
    const float* w_lstm = (const float*)d_in[1];
    const float* b_lstm = (const float*)d_in[2];
    const float* w_conv = (const float*)d_in[3];
    const float* b_conv = (const float*)d_in[4];
    char* ws = (char*)d_ws;
    f16*   wT3 = (f16*)(ws + OFF_WT3);
    float* wc  = (float*)(ws + OFF_WC);
    f16*   xp  = (f16*)(ws + OFF_XP);
    f16*   hA  = (f16*)(ws + OFF_HA);
    f16*   hB  = (f16*)(ws + OFF_HB);
    float* c   = (float*)(ws + OFF_C);

    zero_kernel<<<2048, 256, 0, stream>>>((float4*)(ws + OFF_XP), (int)(ZERO_BYTES / 16));
    wprep<<<3744, 256, 0, stream>>>(w_lstm, wT3);
    wcprep<<<36, 256, 0, stream>>>(w_conv, wc);

    for (int t = 0; t < TT; ++t) {
        const f16* hin  = (t & 1) ? hB : hA;
        f16*       hout = (t & 1) ? hA : hB;
        xprep<<<128, 256, 0, stream>>>(x, xp, t);
        gemm_step<<<1024, 256, 0, stream>>>(xp, hin, wT3, b_lstm, c, hout);
    }
    final_conv<<<128, 256, 0, stream>>>(hA, wc, b_conv, (float*)d_out);
}

// Round 12
// 1036.525 us; speedup vs baseline: 1.0134x; 1.0134x over previous
//
#include <hip/hip_runtime.h>
#include <math.h>

#define BB   8
#define TT   12

typedef _Float16 f16;
typedef f16  f16x8 __attribute__((ext_vector_type(8)));
typedef float f32x4 __attribute__((ext_vector_type(4)));

// ws layout (byte offsets) — halo image is 66*68 = 4488 positions
#define OFF_WT2  0ull            // 8*6*64*296*2        = 1,818,624
#define OFF_WC   1818624ull      // 9*128*8*4           = 36,864    -> 1,855,488
#define OFF_XP   1855488ull      // 8*66*68*64*2        = 4,595,712 -> 6,451,200
#define OFF_HA   6451200ull      // 8*66*68*128*2       = 9,191,424 -> 15,642,624
#define OFF_HB   15642624ull     // 9,191,424           -> 24,834,048
#define OFF_C    24834048ull     // 8*64*64*128*4       = 16,777,216 -> 41,611,264
#define WS_END   41611264ull
#define ZERO_BYTES (WS_END - OFF_XP)   // xp + hA + hB + c = 39,755,776

#define A_BYTES 43008            // 42 DMA KB; 660 pos x 64 B used (dense 32 f16, XOR-swizzled)
#define B_BYTES 37888            // 64 co * 296 k * 2B

__device__ inline void gload16(const void* g, void* l) {
    // LDS dest is the WAVE-UNIFORM base; HW adds lane*16. Global src is per-lane.
    __builtin_amdgcn_global_load_lds((const __attribute__((address_space(1))) void*)g,
                                     (__attribute__((address_space(3))) void*)l, 16, 0, 0);
}

__device__ inline float sigm_fast(float x) {
    return 1.f / (1.f + __expf(-x));
}
__device__ inline float tanh_fast(float x) {
    float xx = fminf(fmaxf(x, -15.f), 15.f);
    float e = __expf(2.f * xx);
    return (e - 1.f) / (e + 1.f);
}

__global__ __launch_bounds__(256) void zero_kernel(float4* __restrict__ p, int n4) {
    int i = blockIdx.x * blockDim.x + threadIdx.x;
    int stride = gridDim.x * blockDim.x;
    for (; i < n4; i += stride) p[i] = make_float4(0.f, 0.f, 0.f, 0.f);
}

// w_lstm (512,192,3,3) fp32 -> wT2 f16 [ntile(8)][chunk(6)][co_l(64)][k(296 pad)]
// co' = hid*4+gate, k = tap*32 + ci_l (k>=288 zero pad)
__global__ __launch_bounds__(256) void wprep(const float* __restrict__ w, f16* __restrict__ wT2) {
    int t = blockIdx.x * 256 + threadIdx.x;
    if (t >= 8 * 6 * 64 * 296) return;
    int k    = t % 296;
    int r    = t / 296;
    int co_l = r & 63;
    int r2   = r >> 6;
    int chunk = r2 % 6;
    int ntl   = r2 / 6;
    f16 val = (f16)0.f;
    if (k < 288) {
        int tap = k >> 5, ci_l = k & 31;
        int ci  = chunk * 32 + ci_l;          // concat(x:0..63, h:64..191) order
        int cop = ntl * 64 + co_l;
        int hid = cop >> 2, gate = cop & 3;
        val = (f16)w[((size_t)(gate * 128 + hid) * 192 + ci) * 9 + tap];
    }
    wT2[t] = val;
}

// w_conv (5,128,3,3) -> wc f32 [tap(9)][ci(128)][8] (cls padded)
__global__ __launch_bounds__(256) void wcprep(const float* __restrict__ w, float* __restrict__ wc) {
    int t = blockIdx.x * 256 + threadIdx.x;
    if (t >= 9216) return;
    int cls = t & 7, ci = (t >> 3) & 127, tap = t >> 10;
    wc[t] = (cls < 5) ? w[(size_t)(cls * 128 + ci) * 9 + tap] : 0.f;
}

// x_t NCHW fp32 -> NHWC f16 with halo: xp[b][y+1][x+1][ci], dims [8][66][68][64]
__global__ __launch_bounds__(256) void xprep(const float* __restrict__ x, f16* __restrict__ xp, int t) {
    int pos = blockIdx.x * 256 + threadIdx.x;     // 32768
    int b = pos >> 12, rr = pos & 4095, y = rr >> 6, xx = rr & 63;
    const float* s = x + ((size_t)(b * TT + t) * 64) * 4096 + y * 64 + xx;
    f16* d = xp + (((size_t)b * 66 + y + 1) * 68 + xx + 1) * 64;
    #pragma unroll
    for (int c8 = 0; c8 < 8; ++c8) {
        f16x8 v;
        #pragma unroll
        for (int e = 0; e < 8; ++e) v[e] = (f16)s[(size_t)(c8 * 8 + e) * 4096];
        *(f16x8*)&d[c8 * 8] = v;
    }
}

__device__ inline float pickc(f32x4 v, int j) {
    return j == 0 ? v[0] : j == 1 ? v[1] : j == 2 ? v[2] : v[3];
}

// Fused gates-GEMM (implicit im2col, f16 MFMA) + LSTM pointwise epilogue.
// Block: 512 pos (8 rows) x 64 co'. 4 waves, each wave = 2 image rows x 64 co'
// (8 mf x 4 nf -> 0.375 ds_reads per MFMA).
// BOTH A and B double-buffered via global_load_lds; ONE barrier per chunk —
// DMA for chunk k+1 issues before compute(k), drained by the chunk-end barrier.
// A is dense [660][32] f16 with 16B-slot XOR swizzle (slot = ci8 ^ ((pc>>1)&3)):
// LDS dest linear (DMA-compatible), global SOURCE pre-permuted per lane (m173),
// reads apply the same XOR -> 2-way banking (free).
// bid = nt*64 + mt: the 8 nt-sharers of slab mt are == mt (mod 8) -> same XCD.
__global__ __launch_bounds__(256, 1) void gemm_step(
    const f16* __restrict__ xp, const f16* __restrict__ hin,
    const f16* __restrict__ wT2, const float* __restrict__ b_lstm,
    float* __restrict__ c_st, f16* __restrict__ hout)
{
    __shared__ __align__(16) char smem[2 * A_BYTES + 2 * B_BYTES];   // 161,792 B
    char* Ab0 = smem;
    char* Ab1 = smem + A_BYTES;
    char* Bb0 = smem + 2 * A_BYTES;
    char* Bb1 = smem + 2 * A_BYTES + B_BYTES;

    const int tid  = threadIdx.x;
    const int lane = tid & 63;
    const int wid  = tid >> 6;                // 0..3; wave owns rows wid*2, wid*2+1
    const int l15  = lane & 15, lg = lane >> 4;

    const int bid = blockIdx.x;
    const int nt  = bid >> 6;                 // 0..7
    const int mt  = bid & 63;                 // 0..63
    const int b   = mt >> 3;
    const int yr  = (mt & 7) << 3;            // first image row of 8-row slab

    const int rowbase = (b * 66 + yr) * 68;   // halo-image position base
    const f16* wslice = wT2 + (size_t)(nt * 6) * 18944;

    f32x4 acc[8][4] = {};

    // ---- per-lane A-DMA source precompute (chunk-invariant) ----
    // DMA instr k stages 16B items k*64+lane; item -> (pc, slot s);
    // slot s holds ci8 = s ^ ((pc>>1)&3)  (inverse of the read-side XOR).
    int poA[11], cxA[11];
    #pragma unroll
    for (int i = 0; i < 11; ++i) {
        int k = wid + i * 4;
        int item = k * 64 + lane;
        int pc = item >> 2;
        int s  = item & 3;
        int pcc = pc < 660 ? pc : 0;          // clamp (pads never read)
        int r = (pcc * 497) >> 15;            // /66 exact for pc<960
        int c = pcc - r * 66;
        poA[i] = rowbase + r * 68 + c;
        cxA[i] = (s ^ ((pcc >> 1) & 3)) * 8;
    }

    auto stageA = [&](int cc, char* Ad) {
        const f16* act; int sh, ci0;
        if (cc < 2) { act = xp;  sh = 6; ci0 = cc * 32; }
        else        { act = hin; sh = 7; ci0 = cc * 32 - 64; }
        #pragma unroll
        for (int i = 0; i < 11; ++i) {
            int k = wid + i * 4;              // uniform per wave
            if (k < 42)
                gload16(act + (((size_t)poA[i]) << sh) + ci0 + cxA[i], Ad + k * 1024);
        }
    };
    auto stageB = [&](int cc, char* Bd) {
        const char* bsrc = (const char*)(wslice + (size_t)cc * 18944);
        for (int k = wid; k < 37; k += 4)     // 37*1024 = 37,888 B
            gload16(bsrc + k * 1024 + lane * 16, Bd + k * 1024);
    };
    auto compute = [&](const char* Abuf, const char* Bbuf) {
        const f16* As  = (const f16*)Abuf;
        const f16* Bsf = (const f16*)Bbuf;
        #pragma unroll
        for (int tap = 0; tap < 9; ++tap) {
            const int dy = tap / 3, dx = tap - dy * 3;
            f16x8 a[8];
            #pragma unroll
            for (int r2 = 0; r2 < 2; ++r2)
                #pragma unroll
                for (int mf = 0; mf < 4; ++mf) {
                    int p = (wid * 2 + r2 + dy) * 66 + mf * 16 + l15 + dx;
                    a[r2 * 4 + mf] = *(const f16x8*)&As[p * 32 + ((lg ^ ((p >> 1) & 3)) << 3)];
                }
            f16x8 bf[4];
            #pragma unroll
            for (int nf = 0; nf < 4; ++nf)
                bf[nf] = *(const f16x8*)&Bsf[(nf * 16 + l15) * 296 + tap * 32 + lg * 8];
            #pragma unroll
            for (int m = 0; m < 8; ++m)
                #pragma unroll
                for (int nf = 0; nf < 4; ++nf)
                    acc[m][nf] = __builtin_amdgcn_mfma_f32_16x16x32_f16(a[m], bf[nf], acc[m][nf], 0, 0, 0);
        }
    };

    // ---- prologue: DMA chunk 0 into buffer 0 ----
    stageA(0, Ab0);
    stageB(0, Bb0);
    __syncthreads();                          // drains prologue DMA

    char* Ac = Ab0; char* Aa = Ab1;
    char* Bc = Bb0; char* Ba = Bb1;

    #pragma unroll 1
    for (int cc = 0; cc < 6; ++cc) {
        if (cc < 5) {
            stageA(cc + 1, Aa);               // async into alt buffers; in flight
            stageB(cc + 1, Ba);               //   across the whole compute phase
        }
        compute(Ac, Bc);
        __syncthreads();                      // drains next-chunk DMA; all reads done
        char* t1 = Ac; Ac = Aa; Aa = t1;
        char* t2 = Bc; Bc = Ba; Ba = t2;
    }

    // ---- LSTM epilogue: 4-gate exchange via shfl_xor within 4-lane groups ----
    const int q = lane & 3;   // gate index of this lane's column (co' = hid*4+gate)
    #pragma unroll
    for (int m = 0; m < 8; ++m) {
        const int r2 = m >> 2, mf = m & 3;
        #pragma unroll
        for (int nf = 0; nf < 4; ++nf) {
            int hid = nt * 16 + nf * 4 + (l15 >> 2);
            float bias = b_lstm[q * 128 + hid];
            f32x4 v = acc[m][nf];
            v[0] += bias; v[1] += bias; v[2] += bias; v[3] += bias;
            float own = pickc(v, q);
            float r1 = __shfl_xor(pickc(v, q ^ 1), 1);
            float rr2 = __shfl_xor(pickc(v, q ^ 2), 2);
            float r3 = __shfl_xor(pickc(v, q ^ 3), 3);
            float gi = q == 0 ? own : (q == 1 ? r1 : q == 2 ? rr2 : r3);
            float gf = q == 1 ? own : (q == 0 ? r1 : q == 3 ? rr2 : r3);
            float go = q == 2 ? own : (q == 3 ? r1 : q == 0 ? rr2 : r3);
            float gg = q == 3 ? own : (q == 2 ? r1 : q == 1 ? rr2 : r3);
            float i_ = sigm_fast(gi);
            float f_ = sigm_fast(gf);
            float o_ = sigm_fast(go);
            float g_ = tanh_fast(gg);
            int px = mf * 16 + lg * 4 + q;    // C row = lg*4 + reg(q)
            int py = yr + wid * 2 + r2;
            size_t ic = (((size_t)b * 64 + py) * 64 + px) * 128 + hid;
            float cv = f_ * c_st[ic] + i_ * g_;
            c_st[ic] = cv;
            float hv = o_ * tanh_fast(cv);
            hout[(((size_t)b * 66 + py + 1) * 68 + (px + 1)) * 128 + hid] = (f16)hv;
        }
    }
}

// Final 3x3 conv (128 -> 5) over NHWC f16 h + channelwise log_softmax (NCHW out)
__global__ __launch_bounds__(256) void final_conv(
    const f16* __restrict__ h, const float* __restrict__ wc,
    const float* __restrict__ b_conv, float* __restrict__ out)
{
    __shared__ float swc[9216];
    for (int i = threadIdx.x; i < 9216; i += 256) swc[i] = wc[i];
    __syncthreads();
    int pos = blockIdx.x * 256 + threadIdx.x;
    int b = pos >> 12, rr = pos & 4095, y = rr >> 6, xx = rr & 63;
    float acc[5];
    #pragma unroll
    for (int cls = 0; cls < 5; ++cls) acc[cls] = b_conv[cls];
    #pragma unroll 1
    for (int tap = 0; tap < 9; ++tap) {
        int dy = tap / 3, dx = tap - dy * 3;
        const f16* hp = h + (((size_t)b * 66 + y + dy) * 68 + xx + dx) * 128;
        #pragma unroll
        for (int c16 = 0; c16 < 16; ++c16) {
            f16x8 v = *(const f16x8*)&hp[c16 * 8];
            #pragma unroll
            for (int e = 0; e < 8; ++e) {
                float hv = (float)v[e];
                const float* wp = &swc[(size_t)(tap * 128 + c16 * 8 + e) * 8];
                acc[0] = fmaf(hv, wp[0], acc[0]);
                acc[1] = fmaf(hv, wp[1], acc[1]);
                acc[2] = fmaf(hv, wp[2], acc[2]);
                acc[3] = fmaf(hv, wp[3], acc[3]);
                acc[4] = fmaf(hv, wp[4], acc[4]);
            }
        }
    }
    float m = acc[0];
    #pragma unroll
    for (int cls = 1; cls < 5; ++cls) m = fmaxf(m, acc[cls]);
    float s = 0.f;
    #pragma unroll
    for (int cls = 0; cls < 5; ++cls) s += __expf(acc[cls] - m);
    float lse = logf(s) + m;
    #pragma unroll
    for (int cls = 0; cls < 5; ++cls)
        out[((size_t)(b * 5 + cls) << 12) + (y << 6) + xx] = acc[cls] - lse;
}

extern "C" void kernel_launch(void* const* d_in, const int* in_sizes, int n_in,
                              void* d_out, int out_size, void* d_ws, size_t ws_size,
                              hipStream_t stream) {
    const float* x      = (const float*)d_in[0];
    const float* w_lstm = (const float*)d_in[1];
    const float* b_lstm = (const float*)d_in[2];
    const float* w_conv = (const float*)d_in[3];
    const float* b_conv = (const float*)d_in[4];
    char* ws = (char*)d_ws;
    f16*   wT2 = (f16*)(ws + OFF_WT2);
    float* wc  = (float*)(ws + OFF_WC);
    f16*   xp  = (f16*)(ws + OFF_XP);
    f16*   hA  = (f16*)(ws + OFF_HA);
    f16*   hB  = (f16*)(ws + OFF_HB);
    float* c   = (float*)(ws + OFF_C);

    zero_kernel<<<2048, 256, 0, stream>>>((float4*)(ws + OFF_XP), (int)(ZERO_BYTES / 16));
    wprep<<<3552, 256, 0, stream>>>(w_lstm, wT2);
    wcprep<<<36, 256, 0, stream>>>(w_conv, wc);

    for (int t = 0; t < TT; ++t) {
        const f16* hin  = (t & 1) ? hB : hA;
        f16*       hout = (t & 1) ? hA : hB;
        xprep<<<128, 256, 0, stream>>>(x, xp, t);
        gemm_step<<<512, 256, 0, stream>>>(xp, hin, wT2, b_lstm, c, hout);
    }
    final_conv<<<128, 256, 0, stream>>>(hA, wc, b_conv, (float*)d_out);
}

// Round 13
// 931.315 us; speedup vs baseline: 1.1278x; 1.1130x over previous
//
#include <hip/hip_runtime.h>
#include <math.h>

#define BB   8
#define TT   12

typedef _Float16 f16;
typedef f16  f16x8 __attribute__((ext_vector_type(8)));
typedef float f32x4 __attribute__((ext_vector_type(4)));

// ws layout (byte offsets) — halo image is 66*68 = 4488 positions
#define OFF_WT2  0ull            // 8*6*64*296*2        = 1,818,624
#define OFF_WC   1818624ull      // 9*128*8*4           = 36,864    -> 1,855,488
#define OFF_XP   1855488ull      // 8*66*68*64*2        = 4,595,712 -> 6,451,200
#define OFF_HA   6451200ull      // 8*66*68*128*2       = 9,191,424 -> 15,642,624
#define OFF_HB   15642624ull     // 9,191,424           -> 24,834,048
#define OFF_C    24834048ull     // 8*64*64*128*4       = 16,777,216 -> 41,611,264
#define WS_END   41611264ull
#define ZERO_BYTES (WS_END - OFF_XP)   // xp + hA + hB + c = 39,755,776

#define A_BYTES 25344            // 396 pos * 32 f16 * 2B, dense, XOR-slot swizzled
#define B_BYTES 37888            // 64 co * 296 k * 2B

__device__ inline void gload16(const void* g, void* l) {
    // LDS dest is the WAVE-UNIFORM base; HW adds lane*16. Global src is per-lane.
    __builtin_amdgcn_global_load_lds((const __attribute__((address_space(1))) void*)g,
                                     (__attribute__((address_space(3))) void*)l, 16, 0, 0);
}

__device__ inline float sigm_fast(float x) {
    return 1.f / (1.f + __expf(-x));
}
__device__ inline float tanh_fast(float x) {
    float xx = fminf(fmaxf(x, -15.f), 15.f);
    float e = __expf(2.f * xx);
    return (e - 1.f) / (e + 1.f);
}

__global__ __launch_bounds__(256) void zero_kernel(float4* __restrict__ p, int n4) {
    int i = blockIdx.x * blockDim.x + threadIdx.x;
    int stride = gridDim.x * blockDim.x;
    for (; i < n4; i += stride) p[i] = make_float4(0.f, 0.f, 0.f, 0.f);
}

// w_lstm (512,192,3,3) fp32 -> wT2 f16 [ntile(8)][chunk(6)][co_l(64)][k(296 pad)]
// co' = hid*4+gate, k = tap*32 + ci_l (k>=288 zero pad)
__global__ __launch_bounds__(256) void wprep(const float* __restrict__ w, f16* __restrict__ wT2) {
    int t = blockIdx.x * 256 + threadIdx.x;
    if (t >= 8 * 6 * 64 * 296) return;
    int k    = t % 296;
    int r    = t / 296;
    int co_l = r & 63;
    int r2   = r >> 6;
    int chunk = r2 % 6;
    int ntl   = r2 / 6;
    f16 val = (f16)0.f;
    if (k < 288) {
        int tap = k >> 5, ci_l = k & 31;
        int ci  = chunk * 32 + ci_l;          // concat(x:0..63, h:64..191) order
        int cop = ntl * 64 + co_l;
        int hid = cop >> 2, gate = cop & 3;
        val = (f16)w[((size_t)(gate * 128 + hid) * 192 + ci) * 9 + tap];
    }
    wT2[t] = val;
}

// w_conv (5,128,3,3) -> wc f32 [tap(9)][ci(128)][8] (cls padded)
__global__ __launch_bounds__(256) void wcprep(const float* __restrict__ w, float* __restrict__ wc) {
    int t = blockIdx.x * 256 + threadIdx.x;
    if (t >= 9216) return;
    int cls = t & 7, ci = (t >> 3) & 127, tap = t >> 10;
    wc[t] = (cls < 5) ? w[(size_t)(cls * 128 + ci) * 9 + tap] : 0.f;
}

// x_t NCHW fp32 -> NHWC f16 with halo: xp[b][y+1][x+1][ci], dims [8][66][68][64]
__global__ __launch_bounds__(256) void xprep(const float* __restrict__ x, f16* __restrict__ xp, int t) {
    int pos = blockIdx.x * 256 + threadIdx.x;     // 32768
    int b = pos >> 12, rr = pos & 4095, y = rr >> 6, xx = rr & 63;
    const float* s = x + ((size_t)(b * TT + t) * 64) * 4096 + y * 64 + xx;
    f16* d = xp + (((size_t)b * 66 + y + 1) * 68 + xx + 1) * 64;
    #pragma unroll
    for (int c8 = 0; c8 < 8; ++c8) {
        f16x8 v;
        #pragma unroll
        for (int e = 0; e < 8; ++e) v[e] = (f16)s[(size_t)(c8 * 8 + e) * 4096];
        *(f16x8*)&d[c8 * 8] = v;
    }
}

__device__ inline float pickc(f32x4 v, int j) {
    return j == 0 ? v[0] : j == 1 ? v[1] : j == 2 ? v[2] : v[3];
}

// Fused gates-GEMM (implicit im2col, f16 MFMA) + LSTM pointwise epilogue.
// Block: 256 pos (4 rows) x 64 co'. 4 waves, each wave = 1 image row x 64 co'.
// A: dense [396][32] f16, 16B-slot XOR swizzle (slot = ci8 ^ ((pc>>1)&3)) ->
//    conflict-free ds_write AND ds_read. Reg-prefetched across the barrier.
// B: single-buffered via global_load_lds (staged post-barrier).
// Chunk-order ROTATION by block parity ((bid>>3)&1)*3: co-resident blocks run
// 3 chunks out of phase, so one block's stage/drain overlaps the other's
// compute (chunk sum is order-invariant). LDS 63.2 KB -> 2 blocks/CU.
// bid = nt*128 + mt: the 8 nt-sharers of slab mt are == mt (mod 8) -> same XCD.
__global__ __launch_bounds__(256, 2) void gemm_step(
    const f16* __restrict__ xp, const f16* __restrict__ hin,
    const f16* __restrict__ wT2, const float* __restrict__ b_lstm,
    float* __restrict__ c_st, f16* __restrict__ hout)
{
    __shared__ __align__(16) char smem[A_BYTES + B_BYTES];   // 63,232 B
    f16* As = (f16*)smem;
    char* Bs = smem + A_BYTES;

    const int tid  = threadIdx.x;
    const int lane = tid & 63;
    const int wid  = tid >> 6;                // 0..3 = image row within slab
    const int l15  = lane & 15, lg = lane >> 4;

    const int bid = blockIdx.x;
    const int nt  = bid >> 7;                 // 0..7
    const int mt  = bid & 127;                // 0..127
    const int b   = mt >> 4;
    const int yr  = (mt & 15) << 2;           // first image row of 4-row slab

    const int rowbase = (b * 66 + yr) * 68;   // halo-image position base
    const f16* wslice = wT2 + (size_t)(nt * 6) * 18944;

    f32x4 acc[4][4] = {};
    f16x8 areg[7];

    // ---- hoisted im2col addressing (chunk-invariant): 1584 items = 396 pc x 4 ci8
    int po[7], wo[7], c8o[7];
    bool av[7];
    #pragma unroll
    for (int i = 0; i < 7; ++i) {
        int idx = i * 256 + tid;
        av[i] = idx < 1584;
        int ci8 = idx & 3;
        int pc  = idx >> 2;                 // 0..395 = r*66+c
        int r   = (pc * 497) >> 15;         // /66 exact for pc<396
        int c   = pc - r * 66;
        po[i]  = rowbase + r * 68 + c;
        c8o[i] = ci8 * 8;
        wo[i]  = pc * 32 + ((ci8 ^ ((pc >> 1) & 3)) << 3);   // XOR slot swizzle
    }

    auto loadA = [&](int cc) {
        if (cc < 2) {
            const f16* src = xp + cc * 32;
            #pragma unroll
            for (int i = 0; i < 7; ++i)
                if (av[i]) areg[i] = *(const f16x8*)(src + ((size_t)po[i] << 6) + c8o[i]);
        } else {
            const f16* src = hin + (cc * 32 - 64);
            #pragma unroll
            for (int i = 0; i < 7; ++i)
                if (av[i]) areg[i] = *(const f16x8*)(src + ((size_t)po[i] << 7) + c8o[i]);
        }
    };
    auto writeA = [&]() {
        #pragma unroll
        for (int i = 0; i < 7; ++i)
            if (av[i]) *(f16x8*)&As[wo[i]] = areg[i];
    };
    auto stageB = [&](int cc) {
        const char* bsrc = (const char*)(wslice + (size_t)cc * 18944);
        for (int k = wid; k < 37; k += 4)           // 37*1024 = 37,888 B
            gload16(bsrc + k * 1024 + lane * 16, Bs + k * 1024);
    };
    auto compute = [&]() {
        const f16* Bsf = (const f16*)Bs;
        #pragma unroll
        for (int tap = 0; tap < 9; ++tap) {
            const int dy = tap / 3, dx = tap - dy * 3;
            f16x8 a[4];
            #pragma unroll
            for (int mf = 0; mf < 4; ++mf) {
                int p = (wid + dy) * 66 + mf * 16 + l15 + dx;
                a[mf] = *(const f16x8*)&As[p * 32 + ((lg ^ ((p >> 1) & 3)) << 3)];
            }
            f16x8 bf[4];
            #pragma unroll
            for (int nf = 0; nf < 4; ++nf)
                bf[nf] = *(const f16x8*)&Bsf[(nf * 16 + l15) * 296 + tap * 32 + lg * 8];
            #pragma unroll
            for (int mf = 0; mf < 4; ++mf)
                #pragma unroll
                for (int nf = 0; nf < 4; ++nf)
                    acc[mf][nf] = __builtin_amdgcn_mfma_f32_16x16x32_f16(a[mf], bf[nf], acc[mf][nf], 0, 0, 0);
        }
    };

    // ---- prologue (rotated start chunk) ----
    const int off = ((bid >> 3) & 1) * 3;     // partner blocks 3 chunks out of phase
    int cur = off;
    loadA(cur);
    stageB(cur);
    writeA();
    __syncthreads();

    #pragma unroll 1
    for (int j = 0; j < 6; ++j) {
        int nxt = (cur == 5) ? 0 : cur + 1;
        if (j < 5) loadA(nxt);        // global->reg, in flight during compute
        compute();
        if (j < 5) {
            __syncthreads();          // all waves done reading As & Bs
            stageB(nxt);              // DMA into B (single buffer, now safe)
            writeA();                 // ds_write prefetched A regs
            __syncthreads();          // drains gloads + A writes
        }
        cur = nxt;
    }

    // ---- LSTM epilogue: 4-gate exchange via shfl_xor within 4-lane groups ----
    const int q = lane & 3;   // gate index of this lane's column (co' = hid*4+gate)
    #pragma unroll
    for (int mf = 0; mf < 4; ++mf) {
        #pragma unroll
        for (int nf = 0; nf < 4; ++nf) {
            int hid = nt * 16 + nf * 4 + (l15 >> 2);
            float bias = b_lstm[q * 128 + hid];
            f32x4 v = acc[mf][nf];
            v[0] += bias; v[1] += bias; v[2] += bias; v[3] += bias;
            float own = pickc(v, q);
            float r1 = __shfl_xor(pickc(v, q ^ 1), 1);
            float r2 = __shfl_xor(pickc(v, q ^ 2), 2);
            float r3 = __shfl_xor(pickc(v, q ^ 3), 3);
            float gi = q == 0 ? own : (q == 1 ? r1 : q == 2 ? r2 : r3);
            float gf = q == 1 ? own : (q == 0 ? r1 : q == 3 ? r2 : r3);
            float go = q == 2 ? own : (q == 3 ? r1 : q == 0 ? r2 : r3);
            float gg = q == 3 ? own : (q == 2 ? r1 : q == 1 ? r2 : r3);
            float i_ = sigm_fast(gi);
            float f_ = sigm_fast(gf);
            float o_ = sigm_fast(go);
            float g_ = tanh_fast(gg);
            int px = mf * 16 + lg * 4 + q;         // C row = lg*4 + reg(q)
            int py = yr + wid;
            size_t ic = (((size_t)b * 64 + py) * 64 + px) * 128 + hid;
            float cv = f_ * c_st[ic] + i_ * g_;
            c_st[ic] = cv;
            float hv = o_ * tanh_fast(cv);
            hout[(((size_t)b * 66 + py + 1) * 68 + (px + 1)) * 128 + hid] = (f16)hv;
        }
    }
}

// Final 3x3 conv (128 -> 5) over NHWC f16 h + channelwise log_softmax (NCHW out)
__global__ __launch_bounds__(256) void final_conv(
    const f16* __restrict__ h, const float* __restrict__ wc,
    const float* __restrict__ b_conv, float* __restrict__ out)
{
    __shared__ float swc[9216];
    for (int i = threadIdx.x; i < 9216; i += 256) swc[i] = wc[i];
    __syncthreads();
    int pos = blockIdx.x * 256 + threadIdx.x;
    int b = pos >> 12, rr = pos & 4095, y = rr >> 6, xx = rr & 63;
    float acc[5];
    #pragma unroll
    for (int cls = 0; cls < 5; ++cls) acc[cls] = b_conv[cls];
    #pragma unroll 1
    for (int tap = 0; tap < 9; ++tap) {
        int dy = tap / 3, dx = tap - dy * 3;
        const f16* hp = h + (((size_t)b * 66 + y + dy) * 68 + xx + dx) * 128;
        #pragma unroll
        for (int c16 = 0; c16 < 16; ++c16) {
            f16x8 v = *(const f16x8*)&hp[c16 * 8];
            #pragma unroll
            for (int e = 0; e < 8; ++e) {
                float hv = (float)v[e];
                const float* wp = &swc[(size_t)(tap * 128 + c16 * 8 + e) * 8];
                acc[0] = fmaf(hv, wp[0], acc[0]);
                acc[1] = fmaf(hv, wp[1], acc[1]);
                acc[2] = fmaf(hv, wp[2], acc[2]);
                acc[3] = fmaf(hv, wp[3], acc[3]);
                acc[4] = fmaf(hv, wp[4], acc[4]);
            }
        }
    }
    float m = acc[0];
    #pragma unroll
    for (int cls = 1; cls < 5; ++cls) m = fmaxf(m, acc[cls]);
    float s = 0.f;
    #pragma unroll
    for (int cls = 0; cls < 5; ++cls) s += __expf(acc[cls] - m);
    float lse = logf(s) + m;
    #pragma unroll
    for (int cls = 0; cls < 5; ++cls)
        out[((size_t)(b * 5 + cls) << 12) + (y << 6) + xx] = acc[cls] - lse;
}

extern "C" void kernel_launch(void* const* d_in, const int* in_sizes, int n_in,
                              void* d_out, int out_size, void* d_ws, size_t ws_size,
                              hipStream_t stream) {
    const float* x      = (const float*)d_in[0];
    const float* w_lstm = (const float*)d_in[1];
    const float* b_lstm = (const float*)d_in[2];
    const float* w_conv = (const float*)d_in[3];
    const float* b_conv = (const float*)d_in[4];
    char* ws = (char*)d_ws;
    f16*   wT2 = (f16*)(ws + OFF_WT2);
    float* wc  = (float*)(ws + OFF_WC);
    f16*   xp  = (f16*)(ws + OFF_XP);
    f16*   hA  = (f16*)(ws + OFF_HA);
    f16*   hB  = (f16*)(ws + OFF_HB);
    float* c   = (float*)(ws + OFF_C);

    zero_kernel<<<2048, 256, 0, stream>>>((float4*)(ws + OFF_XP), (int)(ZERO_BYTES / 16));
    wprep<<<3552, 256, 0, stream>>>(w_lstm, wT2);
    wcprep<<<36, 256, 0, stream>>>(w_conv, wc);

    for (int t = 0; t < TT; ++t) {
        const f16* hin  = (t & 1) ? hB : hA;
        f16*       hout = (t & 1) ? hA : hB;
        xprep<<<128, 256, 0, stream>>>(x, xp, t);
        gemm_step<<<1024, 256, 0, stream>>>(xp, hin, wT2, b_lstm, c, hout);
    }
    final_conv<<<128, 256, 0, stream>>>(hA, wc, b_conv, (float*)d_out);
}

// Round 16
// 903.055 us; speedup vs baseline: 1.1631x; 1.0313x over previous
//
#include <hip/hip_runtime.h>
#include <math.h>

#define BB   8
#define TT   12

typedef _Float16 f16;
typedef f16  f16x8 __attribute__((ext_vector_type(8)));
typedef float f32x4 __attribute__((ext_vector_type(4)));

// ws layout (byte offsets) — halo image is 66*68 = 4488 positions
#define OFF_WT2  0ull            // 8*6*64*296*2        = 1,818,624
#define OFF_WC   1818624ull      // 9*128*8*4           = 36,864    -> 1,855,488
#define OFF_XP   1855488ull      // 8*66*68*64*2        = 4,595,712 -> 6,451,200
#define OFF_HA   6451200ull      // 8*66*68*128*2       = 9,191,424 -> 15,642,624
#define OFF_HB   15642624ull     // 9,191,424           -> 24,834,048
#define OFF_C    24834048ull     // 8*64*64*128*4       = 16,777,216 -> 41,611,264
#define WS_END   41611264ull
#define ZERO_BYTES (WS_END - OFF_XP)   // xp + hA + hB + c = 39,755,776

#define A_BYTES 43008            // 42 KB DMA image; 660 pos x 32 f16 used (XOR-slot swizzled)
#define B_BYTES 37888            // 64 co * 296 k * 2B

__device__ inline void gload16(const void* g, void* l) {
    // LDS dest is the WAVE-UNIFORM base; HW adds lane*16. Global src is per-lane.
    __builtin_amdgcn_global_load_lds((const __attribute__((address_space(1))) void*)g,
                                     (__attribute__((address_space(3))) void*)l, 16, 0, 0);
}

__device__ inline float sigm_fast(float x) {
    return 1.f / (1.f + __expf(-x));
}
__device__ inline float tanh_fast(float x) {
    float xx = fminf(fmaxf(x, -15.f), 15.f);
    float e = __expf(2.f * xx);
    return (e - 1.f) / (e + 1.f);
}

__global__ __launch_bounds__(256) void zero_kernel(float4* __restrict__ p, int n4) {
    int i = blockIdx.x * blockDim.x + threadIdx.x;
    int stride = gridDim.x * blockDim.x;
    for (; i < n4; i += stride) p[i] = make_float4(0.f, 0.f, 0.f, 0.f);
}

// w_lstm (512,192,3,3) fp32 -> wT2 f16 [ntile(8)][chunk(6)][co_l(64)][k(296 pad)]
// co' = hid*4+gate, k = tap*32 + ci_l (k>=288 zero pad)
__global__ __launch_bounds__(256) void wprep(const float* __restrict__ w, f16* __restrict__ wT2) {
    int t = blockIdx.x * 256 + threadIdx.x;
    if (t >= 8 * 6 * 64 * 296) return;
    int k    = t % 296;
    int r    = t / 296;
    int co_l = r & 63;
    int r2   = r >> 6;
    int chunk = r2 % 6;
    int ntl   = r2 / 6;
    f16 val = (f16)0.f;
    if (k < 288) {
        int tap = k >> 5, ci_l = k & 31;
        int ci  = chunk * 32 + ci_l;          // concat(x:0..63, h:64..191) order
        int cop = ntl * 64 + co_l;
        int hid = cop >> 2, gate = cop & 3;
        val = (f16)w[((size_t)(gate * 128 + hid) * 192 + ci) * 9 + tap];
    }
    wT2[t] = val;
}

// w_conv (5,128,3,3) -> wc f32 [tap(9)][ci(128)][8] (cls padded)
__global__ __launch_bounds__(256) void wcprep(const float* __restrict__ w, float* __restrict__ wc) {
    int t = blockIdx.x * 256 + threadIdx.x;
    if (t >= 9216) return;
    int cls = t & 7, ci = (t >> 3) & 127, tap = t >> 10;
    wc[t] = (cls < 5) ? w[(size_t)(cls * 128 + ci) * 9 + tap] : 0.f;
}

// x_t NCHW fp32 -> NHWC f16 with halo: xp[b][y+1][x+1][ci], dims [8][66][68][64]
__global__ __launch_bounds__(256) void xprep(const float* __restrict__ x, f16* __restrict__ xp, int t) {
    int pos = blockIdx.x * 256 + threadIdx.x;     // 32768
    int b = pos >> 12, rr = pos & 4095, y = rr >> 6, xx = rr & 63;
    const float* s = x + ((size_t)(b * TT + t) * 64) * 4096 + y * 64 + xx;
    f16* d = xp + (((size_t)b * 66 + y + 1) * 68 + xx + 1) * 64;
    #pragma unroll
    for (int c8 = 0; c8 < 8; ++c8) {
        f16x8 v;
        #pragma unroll
        for (int e = 0; e < 8; ++e) v[e] = (f16)s[(size_t)(c8 * 8 + e) * 4096];
        *(f16x8*)&d[c8 * 8] = v;
    }
}

__device__ inline float pickc(f32x4 v, int j) {
    return j == 0 ? v[0] : j == 1 ? v[1] : j == 2 ? v[2] : v[3];
}

// Fused gates-GEMM (implicit im2col, f16 MFMA) + LSTM pointwise epilogue.
// Block: 512 pos (8 rows) x 64 co'. 8 waves, each wave = 1 image row x 64 co'.
// BOTH A and B double-buffered, staged purely via global_load_lds; ONE barrier
// per chunk: stage(next)->alt buffers issues BEFORE compute(cur); the chunk-end
// barrier drains DMAs issued a full compute phase earlier -> ~0 exposed latency.
// A: dense [660][32] f16, 16B-slot XOR swizzle (slot = ci8 ^ ((pc>>1)&3));
//    LDS dest linear (DMA), global SOURCE pre-permuted per lane (m173),
//    reads apply the same XOR.
// LDS 161.8 KB -> 1 block/CU, 8 waves = 2 waves/SIMD.
// bid = nt*64 + mt: the 8 nt-sharers of slab mt are == mt (mod 8) -> same XCD.
__global__ __launch_bounds__(512, 1) void gemm_step(
    const f16* __restrict__ xp, const f16* __restrict__ hin,
    const f16* __restrict__ wT2, const float* __restrict__ b_lstm,
    float* __restrict__ c_st, f16* __restrict__ hout)
{
    __shared__ __align__(16) char smem[2 * A_BYTES + 2 * B_BYTES];   // 161,792 B
    char* Ab0 = smem;
    char* Ab1 = smem + A_BYTES;
    char* Bb0 = smem + 2 * A_BYTES;
    char* Bb1 = smem + 2 * A_BYTES + B_BYTES;

    const int tid  = threadIdx.x;
    const int lane = tid & 63;
    const int wid  = tid >> 6;                // 0..7 = image row within slab
    const int l15  = lane & 15, lg = lane >> 4;

    const int bid = blockIdx.x;
    const int nt  = bid >> 6;                 // 0..7
    const int mt  = bid & 63;                 // 0..63
    const int b   = mt >> 3;
    const int yr  = (mt & 7) << 3;            // first image row of 8-row slab

    const int rowbase = (b * 66 + yr) * 68;   // halo-image position base
    const f16* wslice = wT2 + (size_t)(nt * 6) * 18944;

    f32x4 acc[4][4] = {};

    // ---- per-lane A-DMA source precompute (chunk-invariant) ----
    // DMA instr k stages 16B items k*64+lane; item -> (pc, slot s);
    // slot s sources ci8 = s ^ ((pc>>1)&3)  (inverse of the read-side XOR).
    int poA[6], cxA[6];
    #pragma unroll
    for (int i = 0; i < 6; ++i) {
        int k = wid + i * 8;
        int item = k * 64 + lane;
        int pc = item >> 2;
        int s  = item & 3;
        int pcc = pc < 660 ? pc : 0;          // clamp (pad slots never read)
        int r = (pcc * 497) >> 15;            // /66 exact for pc<960
        int c = pcc - r * 66;
        poA[i] = rowbase + r * 68 + c;
        cxA[i] = (s ^ ((pcc >> 1) & 3)) * 8;
    }

    auto stageA = [&](int cc, char* Ad) {
        const f16* act; int sh, ci0;
        if (cc < 2) { act = xp;  sh = 6; ci0 = cc * 32; }
        else        { act = hin; sh = 7; ci0 = cc * 32 - 64; }
        #pragma unroll
        for (int i = 0; i < 6; ++i) {
            int k = wid + i * 8;              // uniform per wave
            if (k < 42)
                gload16(act + (((size_t)poA[i]) << sh) + ci0 + cxA[i], Ad + k * 1024);
        }
    };
    auto stageB = [&](int cc, char* Bd) {
        const char* bsrc = (const char*)(wslice + (size_t)cc * 18944);
        for (int k = wid; k < 37; k += 8)     // 37*1024 = 37,888 B
            gload16(bsrc + k * 1024 + lane * 16, Bd + k * 1024);
    };
    auto compute = [&](const char* Abuf, const char* Bbuf) {
        const f16* As  = (const f16*)Abuf;
        const f16* Bsf = (const f16*)Bbuf;
        #pragma unroll
        for (int tap = 0; tap < 9; ++tap) {
            const int dy = tap / 3, dx = tap - dy * 3;
            f16x8 a[4];
            #pragma unroll
            for (int mf = 0; mf < 4; ++mf) {
                int p = (wid + dy) * 66 + mf * 16 + l15 + dx;
                a[mf] = *(const f16x8*)&As[p * 32 + ((lg ^ ((p >> 1) & 3)) << 3)];
            }
            f16x8 bf[4];
            #pragma unroll
            for (int nf = 0; nf < 4; ++nf)
                bf[nf] = *(const f16x8*)&Bsf[(nf * 16 + l15) * 296 + tap * 32 + lg * 8];
            #pragma unroll
            for (int mf = 0; mf < 4; ++mf)
                #pragma unroll
                for (int nf = 0; nf < 4; ++nf)
                    acc[mf][nf] = __builtin_amdgcn_mfma_f32_16x16x32_f16(a[mf], bf[nf], acc[mf][nf], 0, 0, 0);
        }
    };

    // ---- prologue: DMA chunk 0 into buffer 0 ----
    stageA(0, Ab0);
    stageB(0, Bb0);
    __syncthreads();                          // drains prologue DMA

    char* Ac = Ab0; char* Aa = Ab1;
    char* Bc = Bb0; char* Ba = Bb1;

    #pragma unroll 1
    for (int cc = 0; cc < 6; ++cc) {
        if (cc < 5) {
            stageA(cc + 1, Aa);               // async into alt buffers; in flight
            stageB(cc + 1, Ba);               //   across the whole compute phase
        }
        compute(Ac, Bc);
        __syncthreads();                      // drains next-chunk DMA; all reads done
        char* t1 = Ac; Ac = Aa; Aa = t1;
        char* t2 = Bc; Bc = Ba; Ba = t2;
    }

    // ---- LSTM epilogue: 4-gate exchange via shfl_xor within 4-lane groups ----
    const int q = lane & 3;   // gate index of this lane's column (co' = hid*4+gate)
    #pragma unroll
    for (int mf = 0; mf < 4; ++mf) {
        #pragma unroll
        for (int nf = 0; nf < 4; ++nf) {
            int hid = nt * 16 + nf * 4 + (l15 >> 2);
            float bias = b_lstm[q * 128 + hid];
            f32x4 v = acc[mf][nf];
            v[0] += bias; v[1] += bias; v[2] += bias; v[3] += bias;
            float own = pickc(v, q);
            float r1 = __shfl_xor(pickc(v, q ^ 1), 1);
            float r2 = __shfl_xor(pickc(v, q ^ 2), 2);
            float r3 = __shfl_xor(pickc(v, q ^ 3), 3);
            float gi = q == 0 ? own : (q == 1 ? r1 : q == 2 ? r2 : r3);
            float gf = q == 1 ? own : (q == 0 ? r1 : q == 3 ? r2 : r3);
            float go = q == 2 ? own : (q == 3 ? r1 : q == 0 ? r2 : r3);
            float gg = q == 3 ? own : (q == 2 ? r1 : q == 1 ? r2 : r3);
            float i_ = sigm_fast(gi);
            float f_ = sigm_fast(gf);
            float o_ = sigm_fast(go);
            float g_ = tanh_fast(gg);
            int px = mf * 16 + lg * 4 + q;    // C row = lg*4 + reg(q)
            int py = yr + wid;
            size_t ic = (((size_t)b * 64 + py) * 64 + px) * 128 + hid;
            float cv = f_ * c_st[ic] + i_ * g_;
            c_st[ic] = cv;
            float hv = o_ * tanh_fast(cv);
            hout[(((size_t)b * 66 + py + 1) * 68 + (px + 1)) * 128 + hid] = (f16)hv;
        }
    }
}

// Final 3x3 conv (128 -> 5) over NHWC f16 h + channelwise log_softmax (NCHW out)
__global__ __launch_bounds__(256) void final_conv(
    const f16* __restrict__ h, const float* __restrict__ wc,
    const float* __restrict__ b_conv, float* __restrict__ out)
{
    __shared__ float swc[9216];
    for (int i = threadIdx.x; i < 9216; i += 256) swc[i] = wc[i];
    __syncthreads();
    int pos = blockIdx.x * 256 + threadIdx.x;
    int b = pos >> 12, rr = pos & 4095, y = rr >> 6, xx = rr & 63;
    float acc[5];
    #pragma unroll
    for (int cls = 0; cls < 5; ++cls) acc[cls] = b_conv[cls];
    #pragma unroll 1
    for (int tap = 0; tap < 9; ++tap) {
        int dy = tap / 3, dx = tap - dy * 3;
        const f16* hp = h + (((size_t)b * 66 + y + dy) * 68 + xx + dx) * 128;
        #pragma unroll
        for (int c16 = 0; c16 < 16; ++c16) {
            f16x8 v = *(const f16x8*)&hp[c16 * 8];
            #pragma unroll
            for (int e = 0; e < 8; ++e) {
                float hv = (float)v[e];
                const float* wp = &swc[(size_t)(tap * 128 + c16 * 8 + e) * 8];
                acc[0] = fmaf(hv, wp[0], acc[0]);
                acc[1] = fmaf(hv, wp[1], acc[1]);
                acc[2] = fmaf(hv, wp[2], acc[2]);
                acc[3] = fmaf(hv, wp[3], acc[3]);
                acc[4] = fmaf(hv, wp[4], acc[4]);
            }
        }
    }
    float m = acc[0];
    #pragma unroll
    for (int cls = 1; cls < 5; ++cls) m = fmaxf(m, acc[cls]);
    float s = 0.f;
    #pragma unroll
    for (int cls = 0; cls < 5; ++cls) s += __expf(acc[cls] - m);
    float lse = logf(s) + m;
    #pragma unroll
    for (int cls = 0; cls < 5; ++cls)
        out[((size_t)(b * 5 + cls) << 12) + (y << 6) + xx] = acc[cls] - lse;
}

extern "C" void kernel_launch(void* const* d_in, const int* in_sizes, int n_in,
                              void* d_out, int out_size, void* d_ws, size_t ws_size,
                              hipStream_t stream) {
    const float* x      = (const float*)d_in[0];
    const float* w_lstm = (const float*)d_in[1];
    const float* b_lstm = (const float*)d_in[2];
    const float* w_conv = (const float*)d_in[3];
    const float* b_conv = (const float*)d_in[4];
    char* ws = (char*)d_ws;
    f16*   wT2 = (f16*)(ws + OFF_WT2);
    float* wc  = (float*)(ws + OFF_WC);
    f16*   xp  = (f16*)(ws + OFF_XP);
    f16*   hA  = (f16*)(ws + OFF_HA);
    f16*   hB  = (f16*)(ws + OFF_HB);
    float* c   = (float*)(ws + OFF_C);

    zero_kernel<<<2048, 256, 0, stream>>>((float4*)(ws + OFF_XP), (int)(ZERO_BYTES / 16));
    wprep<<<3552, 256, 0, stream>>>(w_lstm, wT2);
    wcprep<<<36, 256, 0, stream>>>(w_conv, wc);

    for (int t = 0; t < TT; ++t) {
        const f16* hin  = (t & 1) ? hB : hA;
        f16*       hout = (t & 1) ? hA : hB;
        xprep<<<128, 256, 0, stream>>>(x, xp, t);
        gemm_step<<<512, 512, 0, stream>>>(xp, hin, wT2, b_lstm, c, hout);
    }
    final_conv<<<128, 256, 0, stream>>>(hA, wc, b_conv, (float*)d_out);
}

// Round 17
// 872.846 us; speedup vs baseline: 1.2034x; 1.0346x over previous
//
#include <hip/hip_runtime.h>
#include <math.h>

#define BB   8
#define TT   12

typedef _Float16 f16;
typedef f16  f16x8 __attribute__((ext_vector_type(8)));
typedef float f32x4 __attribute__((ext_vector_type(4)));

// ws layout (byte offsets) — halo image is 66*68 = 4488 positions
#define OFF_WT2  0ull            // 8*6*64*296*2        = 1,818,624
#define OFF_WC   1818624ull      // 9*128*8*4           = 36,864    -> 1,855,488
#define OFF_XP   1855488ull      // 8*66*68*64*2        = 4,595,712 -> 6,451,200
#define OFF_HA   6451200ull      // 8*66*68*128*2       = 9,191,424 -> 15,642,624
#define OFF_HB   15642624ull     // 9,191,424           -> 24,834,048
#define OFF_C    24834048ull     // 8*64*64*128*4       = 16,777,216 -> 41,611,264
#define WS_END   41611264ull
#define ZERO_BYTES (WS_END - OFF_XP)   // xp + hA + hB + c = 39,755,776

#define A_BYTES 76800            // 75 KB DMA image; 1188 pos x 32 f16 used (XOR-swizzled)
#define B_BYTES 37888            // 64 co * 296 k * 2B

__device__ inline void gload16(const void* g, void* l) {
    // LDS dest is the WAVE-UNIFORM base; HW adds lane*16. Global src is per-lane.
    __builtin_amdgcn_global_load_lds((const __attribute__((address_space(1))) void*)g,
                                     (__attribute__((address_space(3))) void*)l, 16, 0, 0);
}

__device__ inline float sigm_fast(float x) {
    return 1.f / (1.f + __expf(-x));
}
__device__ inline float tanh_fast(float x) {
    float xx = fminf(fmaxf(x, -15.f), 15.f);
    float e = __expf(2.f * xx);
    return (e - 1.f) / (e + 1.f);
}

__global__ __launch_bounds__(256) void zero_kernel(float4* __restrict__ p, int n4) {
    int i = blockIdx.x * blockDim.x + threadIdx.x;
    int stride = gridDim.x * blockDim.x;
    for (; i < n4; i += stride) p[i] = make_float4(0.f, 0.f, 0.f, 0.f);
}

// w_lstm (512,192,3,3) fp32 -> wT2 f16 [ntile(8)][chunk(6)][co_l(64)][k(296 pad)]
// co' = hid*4+gate, k = tap*32 + ci_l (k>=288 zero pad)
__global__ __launch_bounds__(256) void wprep(const float* __restrict__ w, f16* __restrict__ wT2) {
    int t = blockIdx.x * 256 + threadIdx.x;
    if (t >= 8 * 6 * 64 * 296) return;
    int k    = t % 296;
    int r    = t / 296;
    int co_l = r & 63;
    int r2   = r >> 6;
    int chunk = r2 % 6;
    int ntl   = r2 / 6;
    f16 val = (f16)0.f;
    if (k < 288) {
        int tap = k >> 5, ci_l = k & 31;
        int ci  = chunk * 32 + ci_l;          // concat(x:0..63, h:64..191) order
        int cop = ntl * 64 + co_l;
        int hid = cop >> 2, gate = cop & 3;
        val = (f16)w[((size_t)(gate * 128 + hid) * 192 + ci) * 9 + tap];
    }
    wT2[t] = val;
}

// w_conv (5,128,3,3) -> wc f32 [tap(9)][ci(128)][8] (cls padded)
__global__ __launch_bounds__(256) void wcprep(const float* __restrict__ w, float* __restrict__ wc) {
    int t = blockIdx.x * 256 + threadIdx.x;
    if (t >= 9216) return;
    int cls = t & 7, ci = (t >> 3) & 127, tap = t >> 10;
    wc[t] = (cls < 5) ? w[(size_t)(cls * 128 + ci) * 9 + tap] : 0.f;
}

// x_t NCHW fp32 -> NHWC f16 with halo: xp[b][y+1][x+1][ci], dims [8][66][68][64]
__global__ __launch_bounds__(256) void xprep(const float* __restrict__ x, f16* __restrict__ xp, int t) {
    int pos = blockIdx.x * 256 + threadIdx.x;     // 32768
    int b = pos >> 12, rr = pos & 4095, y = rr >> 6, xx = rr & 63;
    const float* s = x + ((size_t)(b * TT + t) * 64) * 4096 + y * 64 + xx;
    f16* d = xp + (((size_t)b * 66 + y + 1) * 68 + xx + 1) * 64;
    #pragma unroll
    for (int c8 = 0; c8 < 8; ++c8) {
        f16x8 v;
        #pragma unroll
        for (int e = 0; e < 8; ++e) v[e] = (f16)s[(size_t)(c8 * 8 + e) * 4096];
        *(f16x8*)&d[c8 * 8] = v;
    }
}

__device__ inline float pickc(f32x4 v, int j) {
    return j == 0 ? v[0] : j == 1 ? v[1] : j == 2 ? v[2] : v[3];
}

// Fused gates-GEMM (implicit im2col, f16 MFMA) + LSTM pointwise epilogue.
// Block: 1024 pos (16 rows) x 64 co'. 8 waves, each wave = 2 image rows x 64 co'
// (8 mf x 4 nf -> 0.375 ds_reads per MFMA). Grid = 256 = 1 block/CU x ONE round.
// A: single-buffered dense [1188][32] f16, XOR slot swizzle, staged via
//    global_load_lds in the inter-barrier window (75 KB, mostly L2-hit).
// B: double-buffered via global_load_lds, issued BEFORE compute -> in flight
//    across the whole compute phase.
// bid = nt*32 + mt: the 8 nt-sharers of slab mt are == mt (mod 8) -> same XCD.
__global__ __launch_bounds__(512, 1) void gemm_step(
    const f16* __restrict__ xp, const f16* __restrict__ hin,
    const f16* __restrict__ wT2, const float* __restrict__ b_lstm,
    float* __restrict__ c_st, f16* __restrict__ hout)
{
    __shared__ __align__(16) char smem[A_BYTES + 2 * B_BYTES];   // 152,576 B
    char* Ab  = smem;
    char* Bb0 = smem + A_BYTES;
    char* Bb1 = smem + A_BYTES + B_BYTES;

    const int tid  = threadIdx.x;
    const int lane = tid & 63;
    const int wid  = tid >> 6;                // 0..7; wave owns rows 2wid, 2wid+1
    const int l15  = lane & 15, lg = lane >> 4;

    const int bid = blockIdx.x;
    const int nt  = bid >> 5;                 // 0..7
    const int mt  = bid & 31;                 // 0..31
    const int b   = mt >> 2;
    const int yr  = (mt & 3) << 4;            // first image row of 16-row slab

    const int rowbase = (b * 66 + yr) * 68;   // halo-image position base
    const f16* wslice = wT2 + (size_t)(nt * 6) * 18944;

    f32x4 acc[8][4] = {};

    // ---- per-lane A-DMA source precompute (chunk-invariant) ----
    // DMA instr k stages 16B items k*64+lane; item -> (pc, slot s);
    // slot s sources ci8 = s ^ ((pc>>1)&3)  (inverse of the read-side XOR).
    int poA[10], cxA[10];
    #pragma unroll
    for (int i = 0; i < 10; ++i) {
        int k = wid + i * 8;
        int item = k * 64 + lane;
        int pc = item >> 2;
        int s  = item & 3;
        int pcc = pc < 1188 ? pc : 0;         // clamp (pad slots never read)
        int r = (pcc * 15888) >> 20;          // /66 exact for pc < 32768
        int c = pcc - r * 66;
        poA[i] = rowbase + r * 68 + c;
        cxA[i] = (s ^ ((pcc >> 1) & 3)) * 8;
    }

    auto stageA = [&](int cc) {
        const f16* act; int sh, ci0;
        if (cc < 2) { act = xp;  sh = 6; ci0 = cc * 32; }
        else        { act = hin; sh = 7; ci0 = cc * 32 - 64; }
        #pragma unroll
        for (int i = 0; i < 10; ++i) {
            int k = wid + i * 8;              // uniform per wave
            if (k < 75)                       // 75*1024 = 76,800 B >= 1188*64
                gload16(act + (((size_t)poA[i]) << sh) + ci0 + cxA[i], Ab + k * 1024);
        }
    };
    auto stageB = [&](int cc, char* Bd) {
        const char* bsrc = (const char*)(wslice + (size_t)cc * 18944);
        for (int k = wid; k < 37; k += 8)     // 37*1024 = 37,888 B
            gload16(bsrc + k * 1024 + lane * 16, Bd + k * 1024);
    };
    auto compute = [&](const char* Bbuf) {
        const f16* As  = (const f16*)Ab;
        const f16* Bsf = (const f16*)Bbuf;
        #pragma unroll
        for (int tap = 0; tap < 9; ++tap) {
            const int dy = tap / 3, dx = tap - dy * 3;
            f16x8 a[8];
            #pragma unroll
            for (int r2 = 0; r2 < 2; ++r2)
                #pragma unroll
                for (int mf = 0; mf < 4; ++mf) {
                    int p = (wid * 2 + r2 + dy) * 66 + mf * 16 + l15 + dx;
                    a[r2 * 4 + mf] = *(const f16x8*)&As[p * 32 + ((lg ^ ((p >> 1) & 3)) << 3)];
                }
            f16x8 bf[4];
            #pragma unroll
            for (int nf = 0; nf < 4; ++nf)
                bf[nf] = *(const f16x8*)&Bsf[(nf * 16 + l15) * 296 + tap * 32 + lg * 8];
            #pragma unroll
            for (int m = 0; m < 8; ++m)
                #pragma unroll
                for (int nf = 0; nf < 4; ++nf)
                    acc[m][nf] = __builtin_amdgcn_mfma_f32_16x16x32_f16(a[m], bf[nf], acc[m][nf], 0, 0, 0);
        }
    };

    // ---- prologue: DMA chunk 0 ----
    stageA(0);
    stageB(0, Bb0);
    __syncthreads();                          // drains prologue DMA

    char* Bc = Bb0; char* Ba = Bb1;

    #pragma unroll 1
    for (int cc = 0; cc < 6; ++cc) {
        if (cc < 5) stageB(cc + 1, Ba);       // async; in flight across compute
        compute(Bc);
        __syncthreads();                      // next-B drained; all A/B reads done
        if (cc < 5) {
            stageA(cc + 1);                   // single A buffer, now safe
            __syncthreads();                  // drains A DMA (short, L2-hit)
        }
        char* t2 = Bc; Bc = Ba; Ba = t2;
    }

    // ---- LSTM epilogue: 4-gate exchange via shfl_xor within 4-lane groups ----
    const int q = lane & 3;   // gate index of this lane's column (co' = hid*4+gate)
    #pragma unroll
    for (int m = 0; m < 8; ++m) {
        const int r2 = m >> 2, mf = m & 3;
        #pragma unroll
        for (int nf = 0; nf < 4; ++nf) {
            int hid = nt * 16 + nf * 4 + (l15 >> 2);
            float bias = b_lstm[q * 128 + hid];
            f32x4 v = acc[m][nf];
            v[0] += bias; v[1] += bias; v[2] += bias; v[3] += bias;
            float own = pickc(v, q);
            float s1 = __shfl_xor(pickc(v, q ^ 1), 1);
            float s2 = __shfl_xor(pickc(v, q ^ 2), 2);
            float s3 = __shfl_xor(pickc(v, q ^ 3), 3);
            float gi = q == 0 ? own : (q == 1 ? s1 : q == 2 ? s2 : s3);
            float gf = q == 1 ? own : (q == 0 ? s1 : q == 3 ? s2 : s3);
            float go = q == 2 ? own : (q == 3 ? s1 : q == 0 ? s2 : s3);
            float gg = q == 3 ? own : (q == 2 ? s1 : q == 1 ? s2 : s3);
            float i_ = sigm_fast(gi);
            float f_ = sigm_fast(gf);
            float o_ = sigm_fast(go);
            float g_ = tanh_fast(gg);
            int px = mf * 16 + lg * 4 + q;    // C row = lg*4 + reg(q)
            int py = yr + wid * 2 + r2;
            size_t ic = (((size_t)b * 64 + py) * 64 + px) * 128 + hid;
            float cv = f_ * c_st[ic] + i_ * g_;
            c_st[ic] = cv;
            float hv = o_ * tanh_fast(cv);
            hout[(((size_t)b * 66 + py + 1) * 68 + (px + 1)) * 128 + hid] = (f16)hv;
        }
    }
}

// Final 3x3 conv (128 -> 5) over NHWC f16 h + channelwise log_softmax (NCHW out)
__global__ __launch_bounds__(256) void final_conv(
    const f16* __restrict__ h, const float* __restrict__ wc,
    const float* __restrict__ b_conv, float* __restrict__ out)
{
    __shared__ float swc[9216];
    for (int i = threadIdx.x; i < 9216; i += 256) swc[i] = wc[i];
    __syncthreads();
    int pos = blockIdx.x * 256 + threadIdx.x;
    int b = pos >> 12, rr = pos & 4095, y = rr >> 6, xx = rr & 63;
    float acc[5];
    #pragma unroll
    for (int cls = 0; cls < 5; ++cls) acc[cls] = b_conv[cls];
    #pragma unroll 1
    for (int tap = 0; tap < 9; ++tap) {
        int dy = tap / 3, dx = tap - dy * 3;
        const f16* hp = h + (((size_t)b * 66 + y + dy) * 68 + xx + dx) * 128;
        #pragma unroll
        for (int c16 = 0; c16 < 16; ++c16) {
            f16x8 v = *(const f16x8*)&hp[c16 * 8];
            #pragma unroll
            for (int e = 0; e < 8; ++e) {
                float hv = (float)v[e];
                const float* wp = &swc[(size_t)(tap * 128 + c16 * 8 + e) * 8];
                acc[0] = fmaf(hv, wp[0], acc[0]);
                acc[1] = fmaf(hv, wp[1], acc[1]);
                acc[2] = fmaf(hv, wp[2], acc[2]);
                acc[3] = fmaf(hv, wp[3], acc[3]);
                acc[4] = fmaf(hv, wp[4], acc[4]);
            }
        }
    }
    float m = acc[0];
    #pragma unroll
    for (int cls = 1; cls < 5; ++cls) m = fmaxf(m, acc[cls]);
    float s = 0.f;
    #pragma unroll
    for (int cls = 0; cls < 5; ++cls) s += __expf(acc[cls] - m);
    float lse = logf(s) + m;
    #pragma unroll
    for (int cls = 0; cls < 5; ++cls)
        out[((size_t)(b * 5 + cls) << 12) + (y << 6) + xx] = acc[cls] - lse;
}

extern "C" void kernel_launch(void* const* d_in, const int* in_sizes, int n_in,
                              void* d_out, int out_size, void* d_ws, size_t ws_size,
                              hipStream_t stream) {
    const float* x      = (const float*)d_in[0];
    const float* w_lstm = (const float*)d_in[1];
    const float* b_lstm = (const float*)d_in[2];
    const float* w_conv = (const float*)d_in[3];
    const float* b_conv = (const float*)d_in[4];
    char* ws = (char*)d_ws;
    f16*   wT2 = (f16*)(ws + OFF_WT2);
    float* wc  = (float*)(ws + OFF_WC);
    f16*   xp  = (f16*)(ws + OFF_XP);
    f16*   hA  = (f16*)(ws + OFF_HA);
    f16*   hB  = (f16*)(ws + OFF_HB);
    float* c   = (float*)(ws + OFF_C);

    zero_kernel<<<2048, 256, 0, stream>>>((float4*)(ws + OFF_XP), (int)(ZERO_BYTES / 16));
    wprep<<<3552, 256, 0, stream>>>(w_lstm, wT2);
    wcprep<<<36, 256, 0, stream>>>(w_conv, wc);

    for (int t = 0; t < TT; ++t) {
        const f16* hin  = (t & 1) ? hB : hA;
        f16*       hout = (t & 1) ? hA : hB;
        xprep<<<128, 256, 0, stream>>>(x, xp, t);
        gemm_step<<<256, 512, 0, stream>>>(xp, hin, wT2, b_lstm, c, hout);
    }
    final_conv<<<128, 256, 0, stream>>>(hA, wc, b_conv, (float*)d_out);
}